// Round 4
// baseline (756.658 us; speedup 1.0000x reference)
//
#include <hip/hip_runtime.h>

typedef _Float16 f16;
typedef _Float16 f16x8 __attribute__((ext_vector_type(8)));
typedef float f32x4 __attribute__((ext_vector_type(4)));

// address_space(1) = global: forces global_load_* (vmcnt-only) instead of
// flat_load_* (which counts in BOTH vmcnt and lgkmcnt and gets drained by
// every lgkm wait — the r2 serializer).
typedef __attribute__((address_space(1))) const f16 gf16;
typedef __attribute__((address_space(1))) const f16x8 gf16x8;

#define N_TOT   8192
#define L_STEPS 32
#define H_DIM   256
#define OUT_DIM 128
#define BN      32
#define NBLK    256
#define THREADS 512

// workspace layout (bytes):
//   Wpack : 262144 f16 = 524288 B @ 0        (W_hh in B-frag order)
//   fcpack:  32768 f16 =  65536 B @ 524288   (fc_w in B-frag order)
//   bsum  :   1024 f32 =   4096 B @ 589824   (b_ih + b_hh)
#define WPACK_OFF  0
#define FCPACK_OFF 524288
#define BSUM_OFF   589824

__global__ __launch_bounds__(256) void prep_kernel(
    const float* __restrict__ W_hh, const float* __restrict__ fc_w,
    const float* __restrict__ b_ih, const float* __restrict__ b_hh,
    f16* __restrict__ Wpack, f16* __restrict__ fcpack, float* __restrict__ bsum)
{
    int p = blockIdx.x * blockDim.x + threadIdx.x;
    if (p < 262144) {
        // Wpack[((kb*64 + T)*64 + lane)*8 + e] = W_hh[g][k]
        // g = 16*T + (lane&15), k = 32*kb + 8*(lane>>4) + e
        int e = p & 7, lane = (p >> 3) & 63, T = (p >> 9) & 63, kb = p >> 15;
        int g = 16 * T + (lane & 15);
        int k = 32 * kb + 8 * (lane >> 4) + e;
        Wpack[p] = (f16)W_hh[g * 256 + k];
    } else if (p < 262144 + 32768) {
        int p2 = p - 262144;
        // fcpack[((kb*8 + ot)*64 + lane)*8 + e] = fc_w[o][k]
        int e = p2 & 7, lane = (p2 >> 3) & 63, ot = (p2 >> 9) & 7, kb = p2 >> 12;
        int o = 16 * ot + (lane & 15);
        int k = 32 * kb + 8 * (lane >> 4) + e;
        fcpack[p2] = (f16)fc_w[o * 256 + k];
    } else if (p < 262144 + 32768 + 1024) {
        int g = p - 262144 - 32768;
        bsum[g] = b_ih[g] + b_hh[g];
    }
}

__device__ __forceinline__ float sigmoid_(float x) {
    return 1.0f / (1.0f + __expf(-x));
}
__device__ __forceinline__ float tanh_(float x) {
    float t = __expf(-2.0f * x);
    return (1.0f - t) / (1.0f + t);
}

// LDS-only barrier: ds ops complete (lgkmcnt), but global weight loads and
// output stores stay IN FLIGHT across it.
__device__ __forceinline__ void lds_barrier() {
    asm volatile("s_waitcnt lgkmcnt(0)" ::: "memory");
    __builtin_amdgcn_s_barrier();
    asm volatile("" ::: "memory");
}

// 256 blocks x 512 threads (8 waves, 2 waves/SIMD, 1 block/CU).
// Structure per step (ONE barrier per step):
//   [x-proj VALU] [8 gate phases: ds_read a0/a1 -> 16 gate MFMA + 2 fc MFMA
//   (fc REUSES the same A-frags; fc output for step l-1 is computed during
//   step l since hp[buf] == hs[l-1]) + refill just-consumed weight slot]
//   [direct global store of fc(l-1)] [elementwise -> hp[buf^1]] [lds_barrier]
// Weight pipe: 3 slots, uniform depth-3 refill (slot p%3 consumed then
// refilled for its next consumer, which for p>=5 is the NEXT step — those
// loads fly across the elementwise window and the lgkm-only barrier).
// fcw is loaded PRE-ROTATED by kb0 so the phase loop indexes it with
// compile-time p (runtime-indexed reg arrays go to scratch).
__global__ __launch_bounds__(THREADS, 2) void lstm_kernel(
    const float* __restrict__ x, const float* __restrict__ W_ih,
    const f16* __restrict__ Wpack, const float* __restrict__ bsum,
    const f16* __restrict__ fcpack, const float* __restrict__ fc_b,
    float* __restrict__ out)
{
    __shared__ __align__(16) f16 hp[2][8192];  // h in A-frag order, dbuf (32 KB)

    const int tid  = threadIdx.x;
    const int wave = tid >> 6;
    const int lane = tid & 63;
    const int l15  = lane & 15;
    const int lq   = lane >> 4;
    const int n0   = blockIdx.x * BN;
    const int kb0  = (blockIdx.x >> 3) & 7;   // L2 de-hotspot rotation

    // ---- resident fc B-frags, pre-rotated: fcw[p] = frag of kb=(p+kb0)&7 ----
    f16x8 fcw[8];
#pragma unroll
    for (int p = 0; p < 8; ++p) {
        int kb = (p + kb0) & 7;
        fcw[p] = *(const f16x8*)&fcpack[((kb * 8 + wave) * 64 + lane) * 8];
    }

    // h(t=0) = 0
    for (int i = tid; i < 8192; i += THREADS) hp[0][i] = (f16)0.0f;

    // per-lane x-projection constants: g = 256*q + 16*(wave + 8*ti) + l15
    float wih0[2][4], wih1[2][4], bsv[2][4];
#pragma unroll
    for (int ti = 0; ti < 2; ++ti)
#pragma unroll
        for (int q = 0; q < 4; ++q) {
            int g = 256 * q + 16 * (wave + 8 * ti) + l15;
            wih0[ti][q] = W_ih[g * 2 + 0];
            wih1[ti][q] = W_ih[g * 2 + 1];
            bsv[ti][q]  = bsum[g];
        }
    const float fcbv = fc_b[16 * wave + l15];
    const int   ocol = 16 * wave + l15;

    float c[2][2][4];
#pragma unroll
    for (int ti = 0; ti < 2; ++ti)
#pragma unroll
        for (int mt = 0; mt < 2; ++mt)
#pragma unroll
            for (int r = 0; r < 4; ++r) c[ti][mt][r] = 0.0f;

    // weight stream base
    unsigned long long wb_u =
        (unsigned long long)(uintptr_t)(Wpack + wave * 512 + lane * 8);

    // prologue: slots 0,1,2 <- kb0, kb0+1, kb0+2 (consumed at p=0,1,2)
    f16x8 wbuf[3][2][4];  // [slot][ti][q] — slot index always compile-time
    {
        gf16* wb = (gf16*)(uintptr_t)wb_u;
#pragma unroll
        for (int s = 0; s < 3; ++s) {
            int kb = (kb0 + s) & 7;
#pragma unroll
            for (int ti = 0; ti < 2; ++ti)
#pragma unroll
                for (int q = 0; q < 4; ++q)
                    wbuf[s][ti][q] =
                        *(const gf16x8*)&wb[kb * 32768 + q * 8192 + ti * 4096];
        }
    }

    // prefetch x for l=0
    float2 xc[2][4];
#pragma unroll
    for (int mt = 0; mt < 2; ++mt)
#pragma unroll
        for (int r = 0; r < 4; ++r) {
            int n = n0 + 16 * mt + 4 * lq + r;
            xc[mt][r] = *(const float2*)&x[(n * L_STEPS + 0) * 2];
        }

    __syncthreads();  // one-time full sync (h init visible)

    int buf = 0;
#pragma unroll 1
    for (int l = 0; l < L_STEPS; ++l) {
        // Defeat LICM on the l-invariant weight loads (r0 spill bug).
        asm volatile("" : "+v"(wb_u));
        gf16* wb = (gf16*)(uintptr_t)wb_u;

        // ---- accumulator init = x-projection (fp32 exact) ----
        f32x4 acc[2][2][4];  // [ti][mt][q]
#pragma unroll
        for (int mt = 0; mt < 2; ++mt)
#pragma unroll
            for (int r = 0; r < 4; ++r) {
#pragma unroll
                for (int ti = 0; ti < 2; ++ti)
#pragma unroll
                    for (int q = 0; q < 4; ++q)
                        acc[ti][mt][q][r] = bsv[ti][q] + xc[mt][r].x * wih0[ti][q]
                                                       + xc[mt][r].y * wih1[ti][q];
            }

        // fc accumulator for output l-1 (at l=0: consumes h0=0, discarded)
        f32x4 facc0 = {fcbv, fcbv, fcbv, fcbv};
        f32x4 facc1 = facc0;

        // software-prefetch x for l+1
        float2 xn[2][4];
        if (l + 1 < L_STEPS) {
#pragma unroll
            for (int mt = 0; mt < 2; ++mt)
#pragma unroll
                for (int r = 0; r < 4; ++r) {
                    int n = n0 + 16 * mt + 4 * lq + r;
                    xn[mt][r] = *(const float2*)&x[(n * L_STEPS + l + 1) * 2];
                }
        }

        // ---- 8 fused phases: gates(l) + fc(l-1) + weight refill ----
#pragma unroll
        for (int p = 0; p < 8; ++p) {
            const int s    = p % 3;            // slot (compile-time)
            const int kb_c = (p + kb0) & 7;    // kb consumed (addr math only)

            f16x8 a0 = *(const f16x8*)&hp[buf][((kb_c * 2 + 0) * 64 + lane) * 8];
            f16x8 a1 = *(const f16x8*)&hp[buf][((kb_c * 2 + 1) * 64 + lane) * 8];
#pragma unroll
            for (int ti = 0; ti < 2; ++ti)
#pragma unroll
                for (int q = 0; q < 4; ++q) {
                    acc[ti][0][q] = __builtin_amdgcn_mfma_f32_16x16x32_f16(
                        a0, wbuf[s][ti][q], acc[ti][0][q], 0, 0, 0);
                    acc[ti][1][q] = __builtin_amdgcn_mfma_f32_16x16x32_f16(
                        a1, wbuf[s][ti][q], acc[ti][1][q], 0, 0, 0);
                }
            // fused fc (same A-frags, pre-rotated B): out(l-1) accumulation
            facc0 = __builtin_amdgcn_mfma_f32_16x16x32_f16(a0, fcw[p], facc0, 0, 0, 0);
            facc1 = __builtin_amdgcn_mfma_f32_16x16x32_f16(a1, fcw[p], facc1, 0, 0, 0);

            // refill the just-consumed slot for its NEXT consumer:
            // p<=4 -> phase p+3 this step; p=5,6,7 -> next step's phase 2,0,1
            const int pn   = (p <= 4) ? (p + 3) : (p == 5 ? 2 : (p == 6 ? 0 : 1));
            const int kb_n = (pn + kb0) & 7;
#pragma unroll
            for (int ti = 0; ti < 2; ++ti)
#pragma unroll
                for (int q = 0; q < 4; ++q)
                    wbuf[s][ti][q] =
                        *(const gf16x8*)&wb[kb_n * 32768 + q * 8192 + ti * 4096];
        }

        // ---- direct global store of out[:, l-1, :] (64B-segment coalesced,
        //      fire-and-forget; drains during elementwise/barrier) ----
        if (l > 0) {
#pragma unroll
            for (int r = 0; r < 4; ++r) {
                out[((n0 + 4 * lq + r) * L_STEPS + (l - 1)) * OUT_DIM + ocol]      = facc0[r];
                out[((n0 + 16 + 4 * lq + r) * L_STEPS + (l - 1)) * OUT_DIM + ocol] = facc1[r];
            }
        }

        // ---- elementwise LSTM update (all 4 gates in-register per lane) ----
#pragma unroll
        for (int ti = 0; ti < 2; ++ti) {
            int j   = 16 * (wave + 8 * ti) + l15;
            int kbj = j >> 5, qk = (j >> 3) & 3, e = j & 7;
#pragma unroll
            for (int mt = 0; mt < 2; ++mt)
#pragma unroll
                for (int r = 0; r < 4; ++r) {
                    float gi = acc[ti][mt][0][r];
                    float gf = acc[ti][mt][1][r];
                    float gg = acc[ti][mt][2][r];
                    float go = acc[ti][mt][3][r];
                    float cn = sigmoid_(gf) * c[ti][mt][r] + sigmoid_(gi) * tanh_(gg);
                    c[ti][mt][r] = cn;
                    float hv = sigmoid_(go) * tanh_(cn);
                    int laneA = (4 * lq + r) | (qk << 4);
                    hp[buf ^ 1][((kbj * 2 + mt) * 64 + laneA) * 8 + e] = (f16)hv;
                }
        }
        lds_barrier();  // h_new visible; weight prefetch + stores stay in flight

#pragma unroll
        for (int mt = 0; mt < 2; ++mt)
#pragma unroll
            for (int r = 0; r < 4; ++r) xc[mt][r] = xn[mt][r];
        buf ^= 1;
    }

    // ---- epilogue: out[:, 31, :] = fc(hs[31]) ----
    {
        f32x4 e0 = {fcbv, fcbv, fcbv, fcbv};
        f32x4 e1 = e0;
#pragma unroll
        for (int p = 0; p < 8; ++p) {
            const int kb_c = (p + kb0) & 7;
            f16x8 a0 = *(const f16x8*)&hp[buf][((kb_c * 2 + 0) * 64 + lane) * 8];
            f16x8 a1 = *(const f16x8*)&hp[buf][((kb_c * 2 + 1) * 64 + lane) * 8];
            e0 = __builtin_amdgcn_mfma_f32_16x16x32_f16(a0, fcw[p], e0, 0, 0, 0);
            e1 = __builtin_amdgcn_mfma_f32_16x16x32_f16(a1, fcw[p], e1, 0, 0, 0);
        }
#pragma unroll
        for (int r = 0; r < 4; ++r) {
            out[((n0 + 4 * lq + r) * L_STEPS + 31) * OUT_DIM + ocol]      = e0[r];
            out[((n0 + 16 + 4 * lq + r) * L_STEPS + 31) * OUT_DIM + ocol] = e1[r];
        }
    }
}

extern "C" void kernel_launch(void* const* d_in, const int* in_sizes, int n_in,
                              void* d_out, int out_size, void* d_ws, size_t ws_size,
                              hipStream_t stream) {
    const float* x    = (const float*)d_in[0];
    const float* W_ih = (const float*)d_in[1];
    const float* W_hh = (const float*)d_in[2];
    const float* b_ih = (const float*)d_in[3];
    const float* b_hh = (const float*)d_in[4];
    const float* fc_w = (const float*)d_in[5];
    const float* fc_b = (const float*)d_in[6];
    float* out = (float*)d_out;

    char* ws = (char*)d_ws;
    f16*   Wpack  = (f16*)(ws + WPACK_OFF);
    f16*   fcpack = (f16*)(ws + FCPACK_OFF);
    float* bsum   = (float*)(ws + BSUM_OFF);

    const int prep_elems = 262144 + 32768 + 1024;
    prep_kernel<<<(prep_elems + 255) / 256, 256, 0, stream>>>(
        W_hh, fc_w, b_ih, b_hh, Wpack, fcpack, bsum);

    lstm_kernel<<<NBLK, THREADS, 0, stream>>>(
        x, W_ih, Wpack, bsum, fcpack, fc_b, out);
}

// Round 5
// 626.562 us; speedup vs baseline: 1.2076x; 1.2076x over previous
//
#include <hip/hip_runtime.h>

typedef _Float16 f16;
typedef _Float16 f16x8 __attribute__((ext_vector_type(8)));
typedef float f32x4 __attribute__((ext_vector_type(4)));

// address_space(1) = global: forces global_load_* (vmcnt-only) instead of
// flat_load_* (which counts in BOTH vmcnt and lgkmcnt and gets drained by
// every lgkm wait — the r2 serializer).
typedef __attribute__((address_space(1))) const f16 gf16;
typedef __attribute__((address_space(1))) const f16x8 gf16x8;

#define N_TOT   8192
#define L_STEPS 32
#define H_DIM   256
#define OUT_DIM 128
#define BN      32
#define NBLK    256
#define THREADS 512

// workspace layout (bytes):
//   Wpack : 262144 f16 = 524288 B @ 0        (W_hh in B-frag order)
//   fcpack:  32768 f16 =  65536 B @ 524288   (fc_w in B-frag order)
//   bsum  :   1024 f32 =   4096 B @ 589824   (b_ih + b_hh)
#define WPACK_OFF  0
#define FCPACK_OFF 524288
#define BSUM_OFF   589824

__global__ __launch_bounds__(256) void prep_kernel(
    const float* __restrict__ W_hh, const float* __restrict__ fc_w,
    const float* __restrict__ b_ih, const float* __restrict__ b_hh,
    f16* __restrict__ Wpack, f16* __restrict__ fcpack, float* __restrict__ bsum)
{
    int p = blockIdx.x * blockDim.x + threadIdx.x;
    if (p < 262144) {
        // Wpack[((kb*64 + T)*64 + lane)*8 + e] = W_hh[g][k]
        // g = 16*T + (lane&15), k = 32*kb + 8*(lane>>4) + e
        int e = p & 7, lane = (p >> 3) & 63, T = (p >> 9) & 63, kb = p >> 15;
        int g = 16 * T + (lane & 15);
        int k = 32 * kb + 8 * (lane >> 4) + e;
        Wpack[p] = (f16)W_hh[g * 256 + k];
    } else if (p < 262144 + 32768) {
        int p2 = p - 262144;
        // fcpack[((kb*8 + ot)*64 + lane)*8 + e] = fc_w[o][k]
        int e = p2 & 7, lane = (p2 >> 3) & 63, ot = (p2 >> 9) & 7, kb = p2 >> 12;
        int o = 16 * ot + (lane & 15);
        int k = 32 * kb + 8 * (lane >> 4) + e;
        fcpack[p2] = (f16)fc_w[o * 256 + k];
    } else if (p < 262144 + 32768 + 1024) {
        int g = p - 262144 - 32768;
        bsum[g] = b_ih[g] + b_hh[g];
    }
}

__device__ __forceinline__ float sigmoid_(float x) {
    return 1.0f / (1.0f + __expf(-x));
}
__device__ __forceinline__ float tanh_(float x) {
    float t = __expf(-2.0f * x);
    return (1.0f - t) / (1.0f + t);
}

// LDS-only barrier: ds ops complete (lgkmcnt), but global weight loads and
// output stores stay IN FLIGHT across it.
__device__ __forceinline__ void lds_barrier() {
    asm volatile("s_waitcnt lgkmcnt(0)" ::: "memory");
    __builtin_amdgcn_s_barrier();
    asm volatile("" ::: "memory");
}

// 256 blocks x 512 threads (8 waves, 2 waves/SIMD, 1 block/CU).
// Structure per step (ONE barrier per step):
//   [x-proj] [8 fused phases: ds_read a0/a1 -> 16 gate MFMA + 2 fc MFMA
//   (fc output for step l-1 REUSES the same A-frags since hp[buf]==hs[l-1])
//   + refill just-consumed weight slot] [facc -> obuf[ob] (LDS)]
//   [elementwise -> hp[buf^1]] [lds_barrier] [cooperative 512B/row
//   line-contiguous global write of out[:, l-1, :] from obuf[ob]]
// obuf is double-buffered: step l's post-barrier READ of obuf[ob] and step
// l+2's pre-barrier WRITE of obuf[ob] are separated by barrier_{l+1}.
// r4 lesson (FETCH 823 MB / WRITE 874 MB): direct per-lane stores write
// 64B segments of 4 scattered rows -> partial-line RMW at the TCC. The
// obuf staging exists to make whole-line global writes; never remove it.
// Weight pipe: 3 slots, uniform depth-3 refill; slot p%3 consumed then
// refilled for its next consumer (p>=5 -> next step, loads fly across the
// elementwise window and the lgkm-only barrier).
// fcw is loaded PRE-ROTATED by kb0 so the phase loop indexes it with
// compile-time p (runtime-indexed reg arrays go to scratch).
__global__ __launch_bounds__(THREADS, 2) void lstm_kernel(
    const float* __restrict__ x, const float* __restrict__ W_ih,
    const f16* __restrict__ Wpack, const float* __restrict__ bsum,
    const f16* __restrict__ fcpack, const float* __restrict__ fc_b,
    float* __restrict__ out)
{
    __shared__ __align__(16) f16 hp[2][8192];            // h A-frag order, dbuf (32 KB)
    __shared__ __align__(16) float obuf[2][BN * OUT_DIM]; // fc staging, dbuf (32 KB)

    const int tid  = threadIdx.x;
    const int wave = tid >> 6;
    const int lane = tid & 63;
    const int l15  = lane & 15;
    const int lq   = lane >> 4;
    const int n0   = blockIdx.x * BN;
    const int kb0  = (blockIdx.x >> 3) & 7;   // L2 de-hotspot rotation

    // ---- resident fc B-frags, pre-rotated: fcw[p] = frag of kb=(p+kb0)&7 ----
    f16x8 fcw[8];
#pragma unroll
    for (int p = 0; p < 8; ++p) {
        int kb = (p + kb0) & 7;
        fcw[p] = *(const f16x8*)&fcpack[((kb * 8 + wave) * 64 + lane) * 8];
    }

    // h(t=0) = 0
    for (int i = tid; i < 8192; i += THREADS) hp[0][i] = (f16)0.0f;

    // per-lane x-projection constants: g = 256*q + 16*(wave + 8*ti) + l15
    float wih0[2][4], wih1[2][4], bsv[2][4];
#pragma unroll
    for (int ti = 0; ti < 2; ++ti)
#pragma unroll
        for (int q = 0; q < 4; ++q) {
            int g = 256 * q + 16 * (wave + 8 * ti) + l15;
            wih0[ti][q] = W_ih[g * 2 + 0];
            wih1[ti][q] = W_ih[g * 2 + 1];
            bsv[ti][q]  = bsum[g];
        }
    const float fcbv = fc_b[16 * wave + l15];
    const int   ocol = 16 * wave + l15;

    float c[2][2][4];
#pragma unroll
    for (int ti = 0; ti < 2; ++ti)
#pragma unroll
        for (int mt = 0; mt < 2; ++mt)
#pragma unroll
            for (int r = 0; r < 4; ++r) c[ti][mt][r] = 0.0f;

    // weight stream base
    unsigned long long wb_u =
        (unsigned long long)(uintptr_t)(Wpack + wave * 512 + lane * 8);

    // prologue: slots 0,1,2 <- kb0, kb0+1, kb0+2 (consumed at p=0,1,2)
    f16x8 wbuf[3][2][4];  // [slot][ti][q] — slot index always compile-time
    {
        gf16* wb = (gf16*)(uintptr_t)wb_u;
#pragma unroll
        for (int s = 0; s < 3; ++s) {
            int kb = (kb0 + s) & 7;
#pragma unroll
            for (int ti = 0; ti < 2; ++ti)
#pragma unroll
                for (int q = 0; q < 4; ++q)
                    wbuf[s][ti][q] =
                        *(const gf16x8*)&wb[kb * 32768 + q * 8192 + ti * 4096];
        }
    }

    // prefetch x for l=0
    float2 xc[2][4];
#pragma unroll
    for (int mt = 0; mt < 2; ++mt)
#pragma unroll
        for (int r = 0; r < 4; ++r) {
            int n = n0 + 16 * mt + 4 * lq + r;
            xc[mt][r] = *(const float2*)&x[(n * L_STEPS + 0) * 2];
        }

    __syncthreads();  // one-time full sync (h init visible)

    int buf = 0;
#pragma unroll 1
    for (int l = 0; l < L_STEPS; ++l) {
        const int ob = l & 1;
        // Defeat LICM on the l-invariant weight loads (r0 spill bug).
        asm volatile("" : "+v"(wb_u));
        gf16* wb = (gf16*)(uintptr_t)wb_u;

        // ---- accumulator init = x-projection (fp32 exact) ----
        f32x4 acc[2][2][4];  // [ti][mt][q]
#pragma unroll
        for (int mt = 0; mt < 2; ++mt)
#pragma unroll
            for (int r = 0; r < 4; ++r) {
#pragma unroll
                for (int ti = 0; ti < 2; ++ti)
#pragma unroll
                    for (int q = 0; q < 4; ++q)
                        acc[ti][mt][q][r] = bsv[ti][q] + xc[mt][r].x * wih0[ti][q]
                                                       + xc[mt][r].y * wih1[ti][q];
            }

        // fc accumulator for output l-1 (at l=0: consumes h0=0, discarded)
        f32x4 facc0 = {fcbv, fcbv, fcbv, fcbv};
        f32x4 facc1 = facc0;

        // software-prefetch x for l+1
        float2 xn[2][4];
        if (l + 1 < L_STEPS) {
#pragma unroll
            for (int mt = 0; mt < 2; ++mt)
#pragma unroll
                for (int r = 0; r < 4; ++r) {
                    int n = n0 + 16 * mt + 4 * lq + r;
                    xn[mt][r] = *(const float2*)&x[(n * L_STEPS + l + 1) * 2];
                }
        }

        // ---- 8 fused phases: gates(l) + fc(l-1) + weight refill ----
#pragma unroll
        for (int p = 0; p < 8; ++p) {
            const int s    = p % 3;            // slot (compile-time)
            const int kb_c = (p + kb0) & 7;    // kb consumed (addr math only)

            f16x8 a0 = *(const f16x8*)&hp[buf][((kb_c * 2 + 0) * 64 + lane) * 8];
            f16x8 a1 = *(const f16x8*)&hp[buf][((kb_c * 2 + 1) * 64 + lane) * 8];
#pragma unroll
            for (int ti = 0; ti < 2; ++ti)
#pragma unroll
                for (int q = 0; q < 4; ++q) {
                    acc[ti][0][q] = __builtin_amdgcn_mfma_f32_16x16x32_f16(
                        a0, wbuf[s][ti][q], acc[ti][0][q], 0, 0, 0);
                    acc[ti][1][q] = __builtin_amdgcn_mfma_f32_16x16x32_f16(
                        a1, wbuf[s][ti][q], acc[ti][1][q], 0, 0, 0);
                }
            // fused fc (same A-frags, pre-rotated B): out(l-1) accumulation
            facc0 = __builtin_amdgcn_mfma_f32_16x16x32_f16(a0, fcw[p], facc0, 0, 0, 0);
            facc1 = __builtin_amdgcn_mfma_f32_16x16x32_f16(a1, fcw[p], facc1, 0, 0, 0);

            // refill the just-consumed slot for its NEXT consumer:
            // p<=4 -> phase p+3 this step; p=5,6,7 -> next step's phase 2,0,1
            const int pn   = (p <= 4) ? (p + 3) : (p == 5 ? 2 : (p == 6 ? 0 : 1));
            const int kb_n = (pn + kb0) & 7;
#pragma unroll
            for (int ti = 0; ti < 2; ++ti)
#pragma unroll
                for (int q = 0; q < 4; ++q)
                    wbuf[s][ti][q] =
                        *(const gf16x8*)&wb[kb_n * 32768 + q * 8192 + ti * 4096];
        }

        // ---- stage fc(l-1) into LDS (whole-line global writes need this) ----
#pragma unroll
        for (int r = 0; r < 4; ++r) {
            obuf[ob][(4 * lq + r) * OUT_DIM + ocol]        = facc0[r];
            obuf[ob][(16 + 4 * lq + r) * OUT_DIM + ocol]   = facc1[r];
        }

        // ---- elementwise LSTM update (all 4 gates in-register per lane) ----
#pragma unroll
        for (int ti = 0; ti < 2; ++ti) {
            int j   = 16 * (wave + 8 * ti) + l15;
            int kbj = j >> 5, qk = (j >> 3) & 3, e = j & 7;
#pragma unroll
            for (int mt = 0; mt < 2; ++mt)
#pragma unroll
                for (int r = 0; r < 4; ++r) {
                    float gi = acc[ti][mt][0][r];
                    float gf = acc[ti][mt][1][r];
                    float gg = acc[ti][mt][2][r];
                    float go = acc[ti][mt][3][r];
                    float cn = sigmoid_(gf) * c[ti][mt][r] + sigmoid_(gi) * tanh_(gg);
                    c[ti][mt][r] = cn;
                    float hv = sigmoid_(go) * tanh_(cn);
                    int laneA = (4 * lq + r) | (qk << 4);
                    hp[buf ^ 1][((kbj * 2 + mt) * 64 + laneA) * 8 + e] = (f16)hv;
                }
        }
        lds_barrier();  // h_new + obuf[ob] visible; weight prefetch in flight

        // ---- cooperative, line-contiguous global write of out[:, l-1, :] ----
        if (l > 0) {
            const int row = tid >> 4;
            const int gl  = ((n0 + row) * L_STEPS + (l - 1)) * OUT_DIM;
#pragma unroll
            for (int half = 0; half < 2; ++half) {
                int col = (tid & 15) * 4 + half * 64;
                f32x4 v = *(const f32x4*)&obuf[ob][row * OUT_DIM + col];
                *(f32x4*)&out[gl + col] = v;
            }
        }

#pragma unroll
        for (int mt = 0; mt < 2; ++mt)
#pragma unroll
            for (int r = 0; r < 4; ++r) xc[mt][r] = xn[mt][r];
        buf ^= 1;
    }

    // ---- epilogue: out[:, 31, :] = fc(hs[31]) via obuf[0] ----
    {
        f32x4 e0 = {fcbv, fcbv, fcbv, fcbv};
        f32x4 e1 = e0;
#pragma unroll
        for (int p = 0; p < 8; ++p) {
            const int kb_c = (p + kb0) & 7;
            f16x8 a0 = *(const f16x8*)&hp[buf][((kb_c * 2 + 0) * 64 + lane) * 8];
            f16x8 a1 = *(const f16x8*)&hp[buf][((kb_c * 2 + 1) * 64 + lane) * 8];
            e0 = __builtin_amdgcn_mfma_f32_16x16x32_f16(a0, fcw[p], e0, 0, 0, 0);
            e1 = __builtin_amdgcn_mfma_f32_16x16x32_f16(a1, fcw[p], e1, 0, 0, 0);
        }
#pragma unroll
        for (int r = 0; r < 4; ++r) {
            obuf[0][(4 * lq + r) * OUT_DIM + ocol]        = e0[r];
            obuf[0][(16 + 4 * lq + r) * OUT_DIM + ocol]   = e1[r];
        }
        __syncthreads();
        const int row = tid >> 4;
        const int gl  = ((n0 + row) * L_STEPS + 31) * OUT_DIM;
#pragma unroll
        for (int half = 0; half < 2; ++half) {
            int col = (tid & 15) * 4 + half * 64;
            f32x4 v = *(const f32x4*)&obuf[0][row * OUT_DIM + col];
            *(f32x4*)&out[gl + col] = v;
        }
    }
}

extern "C" void kernel_launch(void* const* d_in, const int* in_sizes, int n_in,
                              void* d_out, int out_size, void* d_ws, size_t ws_size,
                              hipStream_t stream) {
    const float* x    = (const float*)d_in[0];
    const float* W_ih = (const float*)d_in[1];
    const float* W_hh = (const float*)d_in[2];
    const float* b_ih = (const float*)d_in[3];
    const float* b_hh = (const float*)d_in[4];
    const float* fc_w = (const float*)d_in[5];
    const float* fc_b = (const float*)d_in[6];
    float* out = (float*)d_out;

    char* ws = (char*)d_ws;
    f16*   Wpack  = (f16*)(ws + WPACK_OFF);
    f16*   fcpack = (f16*)(ws + FCPACK_OFF);
    float* bsum   = (float*)(ws + BSUM_OFF);

    const int prep_elems = 262144 + 32768 + 1024;
    prep_kernel<<<(prep_elems + 255) / 256, 256, 0, stream>>>(
        W_hh, fc_w, b_ih, b_hh, Wpack, fcpack, bsum);

    lstm_kernel<<<NBLK, THREADS, 0, stream>>>(
        x, W_ih, Wpack, bsum, fcpack, fc_b, out);
}

// Round 6
// 453.362 us; speedup vs baseline: 1.6690x; 1.3820x over previous
//
#include <hip/hip_runtime.h>

typedef _Float16 f16;
typedef _Float16 f16x8 __attribute__((ext_vector_type(8)));
typedef float f32x4 __attribute__((ext_vector_type(4)));

// address_space(1) = global: forces global_load_* (vmcnt-only) instead of
// flat_load_* (which counts in BOTH vmcnt and lgkmcnt and gets drained by
// every lgkm wait — the r2 serializer).
typedef __attribute__((address_space(1))) const f16 gf16;
typedef __attribute__((address_space(1))) const f16x8 gf16x8;

#define N_TOT   8192
#define L_STEPS 32
#define H_DIM   256
#define OUT_DIM 128
#define BN      32
#define NBLK    256
#define THREADS 512

// workspace layout (bytes):
//   Wpack : 262144 f16 = 524288 B @ 0        (W_hh in B-frag order)
//   fcpack:  32768 f16 =  65536 B @ 524288   (fc_w in B-frag order)
//   bsum  :   1024 f32 =   4096 B @ 589824   (b_ih + b_hh)
#define WPACK_OFF  0
#define FCPACK_OFF 524288
#define BSUM_OFF   589824

__global__ __launch_bounds__(256) void prep_kernel(
    const float* __restrict__ W_hh, const float* __restrict__ fc_w,
    const float* __restrict__ b_ih, const float* __restrict__ b_hh,
    f16* __restrict__ Wpack, f16* __restrict__ fcpack, float* __restrict__ bsum)
{
    int p = blockIdx.x * blockDim.x + threadIdx.x;
    if (p < 262144) {
        // Wpack[((kb*64 + T)*64 + lane)*8 + e] = W_hh[g][k]
        // g = 16*T + (lane&15), k = 32*kb + 8*(lane>>4) + e
        int e = p & 7, lane = (p >> 3) & 63, T = (p >> 9) & 63, kb = p >> 15;
        int g = 16 * T + (lane & 15);
        int k = 32 * kb + 8 * (lane >> 4) + e;
        Wpack[p] = (f16)W_hh[g * 256 + k];
    } else if (p < 262144 + 32768) {
        int p2 = p - 262144;
        // fcpack[((kb*8 + ot)*64 + lane)*8 + e] = fc_w[o][k]
        int e = p2 & 7, lane = (p2 >> 3) & 63, ot = (p2 >> 9) & 7, kb = p2 >> 12;
        int o = 16 * ot + (lane & 15);
        int k = 32 * kb + 8 * (lane >> 4) + e;
        fcpack[p2] = (f16)fc_w[o * 256 + k];
    } else if (p < 262144 + 32768 + 1024) {
        int g = p - 262144 - 32768;
        bsum[g] = b_ih[g] + b_hh[g];
    }
}

__device__ __forceinline__ float sigmoid_(float x) {
    return 1.0f / (1.0f + __expf(-x));
}
__device__ __forceinline__ float tanh_(float x) {
    float t = __expf(-2.0f * x);
    return (1.0f - t) / (1.0f + t);
}

// LDS-only barrier: ds ops complete (lgkmcnt), but global weight loads and
// output stores stay IN FLIGHT across it.
__device__ __forceinline__ void lds_barrier() {
    asm volatile("s_waitcnt lgkmcnt(0)" ::: "memory");
    __builtin_amdgcn_s_barrier();
    asm volatile("" ::: "memory");
}

// 256 blocks x 512 threads (8 waves, 2 waves/SIMD, 1 block/CU).
// Per step (ONE barrier): [xv from LDS + x-proj] [8 fused phases:
// ds_read a0/a1 -> 16 gate MFMA + 2 fc MFMA (fc for step l-1 reuses the
// same A-frags since hp[buf]==hs[l-1]) + refill just-consumed weight slot]
// [facc -> obuf[ob]] [elementwise -> hp[buf^1]] [lds_barrier]
// [cooperative whole-line global write of out[:, l-1, :] from obuf[ob]].
//
// r4 lesson: direct per-lane out stores -> partial-line RMW at TCC (823 MB
// fetch). obuf staging makes whole-line writes; never remove it.
// r5 lesson: fc fusion + depth-3 weight pipe + reg-resident x overflowed
// the 256-reg unified VGPR/AGPR budget at 2 waves/SIMD -> ~64 B/thread/step
// scratch spill (FETCH 198 MB / WRITE 404 MB). This rev pays for the fusion
// with -64 VGPR: weight pipe depth-2 (wbuf 96->64) and x staged in LDS
// (xc/xn 32 regs -> 8 short-lived temps).
//
// Weight pipe: 2 slots; phase p consumes slot p&1, refills it with
// kb=(p+2+kb0)&7 — for p=6,7 that wraps to the NEXT step's phases 0,1, so
// those loads fly across the elementwise window and the lgkm-only barrier.
// kb sweep rotated per block (kb0) to de-hotspot the per-XCD L2.
// fcw loaded PRE-ROTATED by kb0 so the phase loop indexes it with
// compile-time p (runtime-indexed reg arrays go to scratch).
__global__ __launch_bounds__(THREADS, 2) void lstm_kernel(
    const float* __restrict__ x, const float* __restrict__ W_ih,
    const f16* __restrict__ Wpack, const float* __restrict__ bsum,
    const f16* __restrict__ fcpack, const float* __restrict__ fc_b,
    float* __restrict__ out)
{
    __shared__ __align__(16) f16 hp[2][8192];             // h A-frag order, dbuf (32 KB)
    __shared__ __align__(16) float obuf[2][BN * OUT_DIM]; // fc staging, dbuf (32 KB)
    __shared__ __align__(16) float2 xbuf[BN * 34];        // x slice, padded rows (8.5 KB)

    const int tid  = threadIdx.x;
    const int wave = tid >> 6;
    const int lane = tid & 63;
    const int l15  = lane & 15;
    const int lq   = lane >> 4;
    const int n0   = blockIdx.x * BN;
    const int kb0  = (blockIdx.x >> 3) & 7;   // L2 de-hotspot rotation

    // ---- resident fc B-frags, pre-rotated: fcw[p] = frag of kb=(p+kb0)&7 ----
    f16x8 fcw[8];
#pragma unroll
    for (int p = 0; p < 8; ++p) {
        int kb = (p + kb0) & 7;
        fcw[p] = *(const f16x8*)&fcpack[((kb * 8 + wave) * 64 + lane) * 8];
    }

    // h(t=0) = 0
    for (int i = tid; i < 8192; i += THREADS) hp[0][i] = (f16)0.0f;

    // ---- stage the block's x slice into LDS (8 KB, read once from HBM) ----
    {
        const int row = tid >> 4, part = tid & 15;
        f32x4 v = *(const f32x4*)&x[(n0 + row) * (L_STEPS * 2) + part * 4];
        xbuf[row * 34 + 2 * part + 0] = make_float2(v[0], v[1]);
        xbuf[row * 34 + 2 * part + 1] = make_float2(v[2], v[3]);
    }

    // per-lane x-projection constants: g = 256*q + 16*(wave + 8*ti) + l15
    float wih0[2][4], wih1[2][4], bsv[2][4];
#pragma unroll
    for (int ti = 0; ti < 2; ++ti)
#pragma unroll
        for (int q = 0; q < 4; ++q) {
            int g = 256 * q + 16 * (wave + 8 * ti) + l15;
            wih0[ti][q] = W_ih[g * 2 + 0];
            wih1[ti][q] = W_ih[g * 2 + 1];
            bsv[ti][q]  = bsum[g];
        }
    const float fcbv = fc_b[16 * wave + l15];
    const int   ocol = 16 * wave + l15;

    float c[2][2][4];
#pragma unroll
    for (int ti = 0; ti < 2; ++ti)
#pragma unroll
        for (int mt = 0; mt < 2; ++mt)
#pragma unroll
            for (int r = 0; r < 4; ++r) c[ti][mt][r] = 0.0f;

    // weight stream base
    unsigned long long wb_u =
        (unsigned long long)(uintptr_t)(Wpack + wave * 512 + lane * 8);

    // prologue: slots 0,1 <- kb0, kb0+1 (consumed at p=0,1)
    f16x8 wbuf[2][2][4];  // [slot][ti][q] — slot index always compile-time
    {
        gf16* wb = (gf16*)(uintptr_t)wb_u;
#pragma unroll
        for (int s = 0; s < 2; ++s) {
            int kb = (kb0 + s) & 7;
#pragma unroll
            for (int ti = 0; ti < 2; ++ti)
#pragma unroll
                for (int q = 0; q < 4; ++q)
                    wbuf[s][ti][q] =
                        *(const gf16x8*)&wb[kb * 32768 + q * 8192 + ti * 4096];
        }
    }

    __syncthreads();  // one-time full sync (h init + xbuf visible)

    int buf = 0;
#pragma unroll 1
    for (int l = 0; l < L_STEPS; ++l) {
        const int ob = l & 1;
        // Defeat LICM on the l-invariant weight loads (r0 spill bug).
        asm volatile("" : "+v"(wb_u));
        gf16* wb = (gf16*)(uintptr_t)wb_u;

        // ---- x from LDS (short-lived temps, not loop-carried regs) ----
        float2 xv[2][4];
#pragma unroll
        for (int mt = 0; mt < 2; ++mt)
#pragma unroll
            for (int r = 0; r < 4; ++r)
                xv[mt][r] = xbuf[(16 * mt + 4 * lq + r) * 34 + l];

        // ---- accumulator init = x-projection (fp32 exact) ----
        f32x4 acc[2][2][4];  // [ti][mt][q]
#pragma unroll
        for (int mt = 0; mt < 2; ++mt)
#pragma unroll
            for (int r = 0; r < 4; ++r) {
#pragma unroll
                for (int ti = 0; ti < 2; ++ti)
#pragma unroll
                    for (int q = 0; q < 4; ++q)
                        acc[ti][mt][q][r] = bsv[ti][q] + xv[mt][r].x * wih0[ti][q]
                                                       + xv[mt][r].y * wih1[ti][q];
            }

        // fc accumulator for output l-1 (at l=0: consumes h0=0, discarded)
        f32x4 facc0 = {fcbv, fcbv, fcbv, fcbv};
        f32x4 facc1 = facc0;

        // ---- 8 fused phases: gates(l) + fc(l-1) + weight refill ----
#pragma unroll
        for (int p = 0; p < 8; ++p) {
            const int s    = p & 1;            // slot (compile-time)
            const int kb_c = (p + kb0) & 7;    // kb consumed (addr math only)

            f16x8 a0 = *(const f16x8*)&hp[buf][((kb_c * 2 + 0) * 64 + lane) * 8];
            f16x8 a1 = *(const f16x8*)&hp[buf][((kb_c * 2 + 1) * 64 + lane) * 8];
#pragma unroll
            for (int ti = 0; ti < 2; ++ti)
#pragma unroll
                for (int q = 0; q < 4; ++q) {
                    acc[ti][0][q] = __builtin_amdgcn_mfma_f32_16x16x32_f16(
                        a0, wbuf[s][ti][q], acc[ti][0][q], 0, 0, 0);
                    acc[ti][1][q] = __builtin_amdgcn_mfma_f32_16x16x32_f16(
                        a1, wbuf[s][ti][q], acc[ti][1][q], 0, 0, 0);
                }
            // fused fc (same A-frags, pre-rotated B): out(l-1) accumulation
            facc0 = __builtin_amdgcn_mfma_f32_16x16x32_f16(a0, fcw[p], facc0, 0, 0, 0);
            facc1 = __builtin_amdgcn_mfma_f32_16x16x32_f16(a1, fcw[p], facc1, 0, 0, 0);

            // refill the just-consumed slot for its consumer at p+2;
            // p=6,7 wrap to the NEXT step's phases 0,1 (cross-barrier cover)
            const int kb_n = (p + 2 + kb0) & 7;
#pragma unroll
            for (int ti = 0; ti < 2; ++ti)
#pragma unroll
                for (int q = 0; q < 4; ++q)
                    wbuf[s][ti][q] =
                        *(const gf16x8*)&wb[kb_n * 32768 + q * 8192 + ti * 4096];
        }

        // ---- stage fc(l-1) into LDS (whole-line global writes need this) ----
#pragma unroll
        for (int r = 0; r < 4; ++r) {
            obuf[ob][(4 * lq + r) * OUT_DIM + ocol]        = facc0[r];
            obuf[ob][(16 + 4 * lq + r) * OUT_DIM + ocol]   = facc1[r];
        }

        // ---- elementwise LSTM update (all 4 gates in-register per lane) ----
#pragma unroll
        for (int ti = 0; ti < 2; ++ti) {
            int j   = 16 * (wave + 8 * ti) + l15;
            int kbj = j >> 5, qk = (j >> 3) & 3, e = j & 7;
#pragma unroll
            for (int mt = 0; mt < 2; ++mt)
#pragma unroll
                for (int r = 0; r < 4; ++r) {
                    float gi = acc[ti][mt][0][r];
                    float gf = acc[ti][mt][1][r];
                    float gg = acc[ti][mt][2][r];
                    float go = acc[ti][mt][3][r];
                    float cn = sigmoid_(gf) * c[ti][mt][r] + sigmoid_(gi) * tanh_(gg);
                    c[ti][mt][r] = cn;
                    float hv = sigmoid_(go) * tanh_(cn);
                    int laneA = (4 * lq + r) | (qk << 4);
                    hp[buf ^ 1][((kbj * 2 + mt) * 64 + laneA) * 8 + e] = (f16)hv;
                }
        }
        lds_barrier();  // h_new + obuf[ob] visible; weight prefetch in flight

        // ---- cooperative, line-contiguous global write of out[:, l-1, :] ----
        if (l > 0) {
            const int row = tid >> 4;
            const int gl  = ((n0 + row) * L_STEPS + (l - 1)) * OUT_DIM;
#pragma unroll
            for (int half = 0; half < 2; ++half) {
                int col = (tid & 15) * 4 + half * 64;
                f32x4 v = *(const f32x4*)&obuf[ob][row * OUT_DIM + col];
                *(f32x4*)&out[gl + col] = v;
            }
        }

        buf ^= 1;
    }

    // ---- epilogue: out[:, 31, :] = fc(hs[31]) via obuf[0] ----
    {
        f32x4 e0 = {fcbv, fcbv, fcbv, fcbv};
        f32x4 e1 = e0;
#pragma unroll
        for (int p = 0; p < 8; ++p) {
            const int kb_c = (p + kb0) & 7;
            f16x8 a0 = *(const f16x8*)&hp[buf][((kb_c * 2 + 0) * 64 + lane) * 8];
            f16x8 a1 = *(const f16x8*)&hp[buf][((kb_c * 2 + 1) * 64 + lane) * 8];
            e0 = __builtin_amdgcn_mfma_f32_16x16x32_f16(a0, fcw[p], e0, 0, 0, 0);
            e1 = __builtin_amdgcn_mfma_f32_16x16x32_f16(a1, fcw[p], e1, 0, 0, 0);
        }
#pragma unroll
        for (int r = 0; r < 4; ++r) {
            obuf[0][(4 * lq + r) * OUT_DIM + ocol]        = e0[r];
            obuf[0][(16 + 4 * lq + r) * OUT_DIM + ocol]   = e1[r];
        }
        __syncthreads();
        const int row = tid >> 4;
        const int gl  = ((n0 + row) * L_STEPS + 31) * OUT_DIM;
#pragma unroll
        for (int half = 0; half < 2; ++half) {
            int col = (tid & 15) * 4 + half * 64;
            f32x4 v = *(const f32x4*)&obuf[0][row * OUT_DIM + col];
            *(f32x4*)&out[gl + col] = v;
        }
    }
}

extern "C" void kernel_launch(void* const* d_in, const int* in_sizes, int n_in,
                              void* d_out, int out_size, void* d_ws, size_t ws_size,
                              hipStream_t stream) {
    const float* x    = (const float*)d_in[0];
    const float* W_ih = (const float*)d_in[1];
    const float* W_hh = (const float*)d_in[2];
    const float* b_ih = (const float*)d_in[3];
    const float* b_hh = (const float*)d_in[4];
    const float* fc_w = (const float*)d_in[5];
    const float* fc_b = (const float*)d_in[6];
    float* out = (float*)d_out;

    char* ws = (char*)d_ws;
    f16*   Wpack  = (f16*)(ws + WPACK_OFF);
    f16*   fcpack = (f16*)(ws + FCPACK_OFF);
    float* bsum   = (float*)(ws + BSUM_OFF);

    const int prep_elems = 262144 + 32768 + 1024;
    prep_kernel<<<(prep_elems + 255) / 256, 256, 0, stream>>>(
        W_hh, fc_w, b_ih, b_hh, Wpack, fcpack, bsum);

    lstm_kernel<<<NBLK, THREADS, 0, stream>>>(
        x, W_ih, Wpack, bsum, fcpack, fc_b, out);
}